// Round 6
// baseline (2619.532 us; speedup 1.0000x reference)
//
#include <hip/hip_runtime.h>
#include <cstdint>
#include <cstddef>

#define SEQ   256
#define INP   4
#define BOND  128
#define BATCH 2048
#define MATSZ (BOND*BOND)

typedef __bf16 bf16x8 __attribute__((ext_vector_type(8)));
typedef __bf16 bf16x4 __attribute__((ext_vector_type(4)));
typedef float  f32x4  __attribute__((ext_vector_type(4)));
typedef short  s16x4  __attribute__((ext_vector_type(4)));

// ---- workspace layout (bytes) ----
static constexpr size_t SZ_MAT   = (size_t)SEQ*INP*MATSZ*2;   // 32 MiB each
static constexpr size_t OFF_ABF  = 0;
static constexpr size_t OFF_ATBF = OFF_ABF + SZ_MAT;
static constexpr size_t OFF_BHI  = OFF_ATBF + SZ_MAT;
static constexpr size_t OFF_BLO  = OFF_BHI + SZ_MAT;
static constexpr size_t SZ_MWS   = 2ull*MATSZ*2;              // 2 chains final M (bf16, linear)
static constexpr size_t SZ_TAIL  = SZ_MWS + (size_t)BATCH*4 + 64;

static __device__ __forceinline__ unsigned short f2bf(float f) {
    union { float f; uint32_t u; } v; v.f = f;
    uint32_t r = (v.u + 0x7FFFu + ((v.u >> 16) & 1u)) >> 16;   // RNE
    return (unsigned short)r;
}
static __device__ __forceinline__ float bf2f(unsigned short b) {
    union { uint32_t u; float f; } v; v.u = ((uint32_t)b) << 16;
    return v.f;
}
static __device__ __forceinline__ f32x4 mfma16(bf16x8 a, bf16x8 b, f32x4 c) {
    return __builtin_amdgcn_mfma_f32_16x16x32_bf16(a, b, c, 0, 0, 0);
}
#if defined(__has_builtin)
#if __has_builtin(__builtin_amdgcn_mfma_f32_16x16x16bf16_1k)
#define HAVE_MFMA16X16_BUILTIN 1
#endif
#endif
static __device__ __forceinline__ f32x4 mfma16x16(bf16x4 a, bf16x4 b, f32x4 c) {
#ifdef HAVE_MFMA16X16_BUILTIN
    return __builtin_amdgcn_mfma_f32_16x16x16bf16_1k(
        __builtin_bit_cast(s16x4, a), __builtin_bit_cast(s16x4, b), c, 0, 0, 0);
#else
    asm("v_mfma_f32_16x16x16_bf16 %0, %1, %2, %0" : "+v"(c) : "v"(a), "v"(b));
    return c;
#endif
}
static __device__ __forceinline__ unsigned int cvtpk(float a, float b) {
    unsigned int d;
    asm("v_cvt_pk_bf16_f32 %0, %1, %2" : "=v"(d) : "v"(a), "v"(b));
    return d;   // lo16 = bf16(a), hi16 = bf16(b)
}
// XOR-swizzled LDS layout: matrix stored as 16B chunks; chunk (r, c8) at
// slot r*16 + (c8 ^ (r&15)). Returns SHORT index of chunk start.
static __device__ __forceinline__ int xoff(int r, int c8) {
    return ((r << 4) + (c8 ^ (r & 15))) << 3;
}
// async global->LDS 16B, linear LDS dest (lane*16), pre-swizzled global source
static __device__ __forceinline__ void gload_lds16(const unsigned short* g, unsigned short* l) {
    __builtin_amdgcn_global_load_lds((const __attribute__((address_space(1))) unsigned int*)g,
                                     (__attribute__((address_space(3))) unsigned int*)l,
                                     16, 0, 0);
}
// stage one 128x128 bf16 matrix into XOR-swizzled LDS (all 512 threads)
static __device__ __forceinline__ void stage_mat(const unsigned short* __restrict__ Ai,
                                                 unsigned short* dst, int tid) {
#pragma unroll
    for (int j = 0; j < 4; ++j) {
        int slot = j * 512 + tid;
        int r = slot >> 4, c8 = slot & 15;
        const unsigned short* src = Ai + (size_t)r * BOND + ((c8 ^ (r & 15)) << 3);
        unsigned short* ldst = dst + (size_t)(j * 512 + (tid & ~63)) * 8;
        gload_lds16(src, ldst);
    }
}

// ---------------- convert: fp32 core -> bf16 A, bf16 A^T, bf16 hi/lo of (A - I) ----------------
__global__ void convert_kernel(const float* __restrict__ core,
                               unsigned short* __restrict__ abf,
                               unsigned short* __restrict__ atbf,
                               unsigned short* __restrict__ bhi,
                               unsigned short* __restrict__ blo,
                               int use_blo) {
    __shared__ unsigned short tile[BOND][BOND + 2];
    const int mat = blockIdx.x;                       // 0..1023  (t*4+v)
    const float* src = core + (size_t)mat * MATSZ;
    unsigned short* dA = abf  + (size_t)mat * MATSZ;
    unsigned short* dT = atbf + (size_t)mat * MATSZ;
    unsigned short* dH = bhi  + (size_t)mat * MATSZ;
    unsigned short* dL = blo  + (size_t)mat * MATSZ;
    const int tid = threadIdx.x;
    for (int j = 0; j < 16; ++j) {
        int lin4 = (tid + j * 256) * 4;
        float4 f = *(const float4*)(src + lin4);
        int r = lin4 >> 7, c = lin4 & 127;
        unsigned short a0=f2bf(f.x), a1=f2bf(f.y), a2=f2bf(f.z), a3=f2bf(f.w);
        *(ushort4*)(dA + lin4) = make_ushort4(a0,a1,a2,a3);
        tile[r][c]=a0; tile[r][c+1]=a1; tile[r][c+2]=a2; tile[r][c+3]=a3;
        float b0 = f.x - ((r == c    ) ? 1.0f : 0.0f);
        float b1 = f.y - ((r == c + 1) ? 1.0f : 0.0f);
        float b2 = f.z - ((r == c + 2) ? 1.0f : 0.0f);
        float b3 = f.w - ((r == c + 3) ? 1.0f : 0.0f);
        unsigned short h0=f2bf(b0), h1=f2bf(b1), h2=f2bf(b2), h3=f2bf(b3);
        *(ushort4*)(dH + lin4) = make_ushort4(h0,h1,h2,h3);
        if (use_blo) {
            *(ushort4*)(dL + lin4) = make_ushort4(
                f2bf(b0 - bf2f(h0)), f2bf(b1 - bf2f(h1)),
                f2bf(b2 - bf2f(h2)), f2bf(b3 - bf2f(h3)));
        }
    }
    __syncthreads();
    for (int j = 0; j < 16; ++j) {
        int lin4 = (tid + j * 256) * 4;
        int co = lin4 >> 7, r0 = lin4 & 127;
        *(ushort4*)(dT + lin4) = make_ushort4(tile[r0][co], tile[r0+1][co],
                                              tile[r0+2][co], tile[r0+3][co]);
    }
}

// ---------------- main kernel: blocks 0..1 = Z chains, 2..65 = amplitude ----------------
struct ZSm {
    unsigned short As[2][MATSZ];    // double-buffered A_i, XOR layout (64 KB)
    unsigned short M[MATSZ];        // density matrix, XOR layout (32 KB)
    float vec[BOND];
};
struct ASm {
    int   toks[SEQ * 32];           // prefetched tokens (32 KB)
    float hf[32][132];              // fp32 h state [batch-col][dim]
    unsigned short hhi[32 * BOND];  // bf16 hi of h, XOR layout (flat)
    unsigned short hlo[32 * BOND];  // bf16 lo of h, XOR layout (flat)
    float ev[BOND];
    float partial[8][32];
    float sinv[32];
    float logn[32];
};
union SmU { ZSm z; ASm a; };

template<int USE_BLO>
__global__ __launch_bounds__(512) void main_kernel(
        const int*   __restrict__ xdata,
        const float* __restrict__ edge,
        const unsigned short* __restrict__ abf,
        const unsigned short* __restrict__ atbf,
        const unsigned short* __restrict__ bhi,
        const unsigned short* __restrict__ blo,
        unsigned short* __restrict__ mws,
        float* __restrict__ logamp) {
    __shared__ SmU sm;
    const int tid = threadIdx.x;
    const int l   = tid & 63;
    const int w   = tid >> 6;          // wave 0..7
    const int lo  = l & 15;
    const int hi  = l >> 4;            // 0..3

    if (blockIdx.x < 2) {
        // ================= Z chain: 4 compute waves + 4 stage-helper waves =================
        // Per token i: T = A_i M computed in SWAPPED form C1 = M*A_i^T (M symmetric),
        // so C1[p][q] = T[q][p] lands with T-row = lane&15, k(=p) = 4*hi+reg — exactly the
        // A-fragment layout of v_mfma_f32_16x16x16_bf16. T never touches LDS.
        // P2: accM[m][c] += sum_n T[m][n] * A_i[c][n]  (A_i rows as B-frags, K=16 steps).
        const int chain = blockIdx.x;                  // 0 = fwd (alpha), 1 = bwd (omega, A^T)
        const unsigned short* Abase = chain ? atbf : abf;

        if (tid < BOND) sm.z.vec[tid] = edge[chain * BOND + tid];
        __syncthreads();
        for (int idx = tid; idx < MATSZ; idx += 512) {
            int r = idx >> 7, c = idx & 127;
            sm.z.M[xoff(r, c >> 3) + (c & 7)] = f2bf(sm.z.vec[r] * sm.z.vec[c]);
        }
        stage_mat(Abase + (size_t)(chain ? (SEQ - 1) : 0) * INP * MATSZ, sm.z.As[0], tid);
        __syncthreads();               // M0 + As[0] ready (full drain, once)

        int cur = 0;
        for (int s = 1; s <= 128; ++s) {
            const int tstep = chain ? (SEQ - s) : (s - 1);
            const unsigned short* As_g = Abase + (size_t)tstep * INP * MATSZ;
            f32x4 accM[2][8];
#pragma unroll
            for (int mt = 0; mt < 2; ++mt)
#pragma unroll
                for (int ct = 0; ct < 8; ++ct) accM[mt][ct] = (f32x4){0.f, 0.f, 0.f, 0.f};

            for (int i = 0; i < 4; ++i) {
                // issue staging of the next matrix (all 8 waves, 4 x 16B each)
                const unsigned short* nxt = nullptr;
                if (i < 3)           nxt = As_g + (size_t)(i + 1) * MATSZ;
                else if (s < 128)    nxt = Abase + (size_t)(chain ? (SEQ - s - 1) : s) * INP * MATSZ;
                if (nxt) stage_mat(nxt, sm.z.As[cur ^ 1], tid);

                if (w < 4) {
                    const unsigned short* Ac = sm.z.As[cur];
                    // ---- P1: C1 = M * A_i^T, region p=0..127, q = wave's 32 rows ----
                    f32x4 acc1[8][2];
#pragma unroll
                    for (int pt = 0; pt < 8; ++pt) {
                        acc1[pt][0] = (f32x4){0.f, 0.f, 0.f, 0.f};
                        acc1[pt][1] = (f32x4){0.f, 0.f, 0.f, 0.f};
                    }
#pragma unroll
                    for (int kk = 0; kk < 4; ++kk) {
                        bf16x8 bq0 = *(const bf16x8*)&Ac[xoff(w * 32 + lo,      kk * 4 + hi)];
                        bf16x8 bq1 = *(const bf16x8*)&Ac[xoff(w * 32 + 16 + lo, kk * 4 + hi)];
#pragma unroll
                        for (int pt = 0; pt < 8; ++pt) {
                            bf16x8 mf = *(const bf16x8*)&sm.z.M[xoff(pt * 16 + lo, kk * 4 + hi)];
                            acc1[pt][0] = mfma16(mf, bq0, acc1[pt][0]);
                            acc1[pt][1] = mfma16(mf, bq1, acc1[pt][1]);
                        }
                    }
                    // ---- convert T to bf16 A-frags in-register ----
                    bf16x4 tf[2][8];
#pragma unroll
                    for (int pt = 0; pt < 8; ++pt)
#pragma unroll
                        for (int mt = 0; mt < 2; ++mt) {
                            union { unsigned int u[2]; bf16x4 v; } pk;
                            pk.u[0] = cvtpk(acc1[pt][mt][0], acc1[pt][mt][1]);
                            pk.u[1] = cvtpk(acc1[pt][mt][2], acc1[pt][mt][3]);
                            tf[mt][pt] = pk.v;
                        }
                    // ---- P2: accM += T * A_i^T  (16x16x16, B = A_i rows, 8B reads) ----
#pragma unroll
                    for (int ks = 0; ks < 8; ++ks) {
#pragma unroll
                        for (int ct = 0; ct < 8; ++ct) {
                            bf16x4 bb = *(const bf16x4*)&Ac[xoff(ct * 16 + lo, 2 * ks + (hi >> 1)) + 4 * (hi & 1)];
                            accM[0][ct] = mfma16x16(tf[0][ks], bb, accM[0][ct]);
                            accM[1][ct] = mfma16x16(tf[1][ks], bb, accM[1][ct]);
                        }
                    }
                }
                asm volatile("s_waitcnt vmcnt(0)" ::: "memory");   // own staged loads landed
                __builtin_amdgcn_s_barrier();                      // all waves' staging visible
                cur ^= 1;
            }
            // ---- step end: write M' (scaled 1/4) ----
            if (w < 4) {
#pragma unroll
                for (int mt = 0; mt < 2; ++mt)
#pragma unroll
                    for (int ct = 0; ct < 8; ++ct)
#pragma unroll
                        for (int r = 0; r < 4; ++r) {
                            int row = w * 32 + mt * 16 + hi * 4 + r;
                            int col = ct * 16 + lo;
                            sm.z.M[xoff(row, col >> 3) + (col & 7)] =
                                f2bf(accM[mt][ct][r] * 0.25f);
                        }
            }
            asm volatile("s_waitcnt lgkmcnt(0)" ::: "memory");
            __builtin_amdgcn_s_barrier();                          // M' visible to all
        }
        // publish final M (XOR layout -> linear global)
        unsigned short* outb = mws + (size_t)chain * MATSZ;
        for (int j = 0; j < 4; ++j) {
            int chunk = tid + j * 512;
            int r = chunk >> 4, c8 = chunk & 15;
            *(bf16x8*)(outb + (size_t)r * BOND + c8 * 8) =
                *(const bf16x8*)&sm.z.M[xoff(r, c8)];
        }
    } else {
        // ================= amplitude scan (unchanged from passing r5) =================
        const int lr = lo, lq = hi;
        const int b0 = (blockIdx.x - 2) * 32;
        for (int j = 0; j < 16; ++j) {
            int idx = tid + j * 512;
            int t = idx >> 5, c = idx & 31;
            sm.a.toks[idx] = xdata[(size_t)t * BATCH + b0 + c];
        }
        if (tid < BOND) sm.a.ev[tid] = edge[tid];      // alpha
        if (tid < 32)  sm.a.logn[tid] = 0.f;
        __syncthreads();
        for (int idx = tid; idx < 32 * BOND; idx += 512) {
            int c = idx >> 7, r = idx & 127;
            float v = sm.a.ev[r];
            unsigned short hh = f2bf(v);
            sm.a.hf[c][r] = v;
            int si = xoff(c, r >> 3) + (r & 7);
            sm.a.hhi[si] = hh;
            sm.a.hlo[si] = f2bf(v - bf2f(hh));
        }
        __syncthreads();

        for (int t = 0; t < SEQ; ++t) {
            const unsigned short* Bh = bhi + (size_t)t * INP * MATSZ;
            const unsigned short* Bl = blo + (size_t)t * INP * MATSZ;
            bf16x8 bh[4][4], bl[4][4];
#pragma unroll
            for (int kk = 0; kk < 4; ++kk)
#pragma unroll
                for (int v = 0; v < 4; ++v) {
                    size_t ro = (size_t)v * MATSZ + (size_t)(w * 16 + lr) * BOND + kk * 32 + lq * 8;
                    bh[kk][v] = *(const bf16x8*)(Bh + ro);
                    if (USE_BLO) bl[kk][v] = *(const bf16x8*)(Bl + ro);
                }
            f32x4 acc[4][2] = {};
#pragma unroll
            for (int kk = 0; kk < 4; ++kk) {
                bf16x8 hh0 = *(const bf16x8*)&sm.a.hhi[xoff(lr,      kk * 4 + lq)];
                bf16x8 hh1 = *(const bf16x8*)&sm.a.hhi[xoff(16 + lr, kk * 4 + lq)];
                bf16x8 hl0 = *(const bf16x8*)&sm.a.hlo[xoff(lr,      kk * 4 + lq)];
                bf16x8 hl1 = *(const bf16x8*)&sm.a.hlo[xoff(16 + lr, kk * 4 + lq)];
#pragma unroll
                for (int v = 0; v < 4; ++v) {
                    acc[v][0] = mfma16(bh[kk][v], hh0, acc[v][0]);
                    acc[v][0] = mfma16(bh[kk][v], hl0, acc[v][0]);
                    acc[v][1] = mfma16(bh[kk][v], hh1, acc[v][1]);
                    acc[v][1] = mfma16(bh[kk][v], hl1, acc[v][1]);
                    if (USE_BLO) {
                        acc[v][0] = mfma16(bl[kk][v], hh0, acc[v][0]);
                        acc[v][1] = mfma16(bl[kk][v], hh1, acc[v][1]);
                    }
                }
            }
            __syncthreads();
            f32x4 h2[2];
#pragma unroll
            for (int ct = 0; ct < 2; ++ct) {
                int tok = sm.a.toks[t * 32 + ct * 16 + lr];
                f32x4 d = acc[0][ct];
                d = (tok == 1) ? acc[1][ct] : d;
                d = (tok == 2) ? acc[2][ct] : d;
                d = (tok == 3) ? acc[3][ct] : d;
                f32x4 ho = *(const f32x4*)&sm.a.hf[ct * 16 + lr][w * 16 + lq * 4];
                h2[ct] = ho + d;
            }
            if ((t & 7) == 7) {
#pragma unroll
                for (int ct = 0; ct < 2; ++ct) {
                    float ss = h2[ct][0]*h2[ct][0] + h2[ct][1]*h2[ct][1]
                             + h2[ct][2]*h2[ct][2] + h2[ct][3]*h2[ct][3];
                    ss += __shfl_xor(ss, 16);
                    ss += __shfl_xor(ss, 32);
                    if (lq == 0) sm.a.partial[w][ct * 16 + lr] = ss;
                }
                __syncthreads();
                if (tid < 32) {
                    float s2 = 0.f;
#pragma unroll
                    for (int w2 = 0; w2 < 8; ++w2) s2 += sm.a.partial[w2][tid];
                    sm.a.sinv[tid] = rsqrtf(s2);
                    sm.a.logn[tid] += 0.5f * logf(s2);
                }
                __syncthreads();
#pragma unroll
                for (int ct = 0; ct < 2; ++ct) h2[ct] *= sm.a.sinv[ct * 16 + lr];
            }
#pragma unroll
            for (int ct = 0; ct < 2; ++ct) {
                int c = ct * 16 + lr;
                *(f32x4*)&sm.a.hf[c][w * 16 + lq * 4] = h2[ct];
                unsigned short q0 = f2bf(h2[ct][0]), q1 = f2bf(h2[ct][1]),
                               q2 = f2bf(h2[ct][2]), q3 = f2bf(h2[ct][3]);
                int c8w = w * 2 + (lq >> 1);
                int si  = xoff(c, c8w) + (lq & 1) * 4;
                *(ushort4*)&sm.a.hhi[si] = make_ushort4(q0, q1, q2, q3);
                *(ushort4*)&sm.a.hlo[si] =
                    make_ushort4(f2bf(h2[ct][0] - bf2f(q0)), f2bf(h2[ct][1] - bf2f(q1)),
                                 f2bf(h2[ct][2] - bf2f(q2)), f2bf(h2[ct][3] - bf2f(q3)));
            }
            __syncthreads();
        }
        if (tid < BOND) sm.a.ev[tid] = edge[BOND + tid];  // omega
        __syncthreads();
        if (tid < 32) {
            float dot = 0.f;
            for (int r = 0; r < BOND; ++r) dot += sm.a.hf[tid][r] * sm.a.ev[r];
            logamp[b0 + tid] = 2.f * (logf(fabsf(dot)) + sm.a.logn[tid]);
        }
    }
}

// ---------------- finalize: logZ = log<M_fwd, M_bwd> + 256*log4; out = logamp - logZ ----------------
__global__ __launch_bounds__(1024) void fin_kernel(const unsigned short* __restrict__ mws,
                                                   const float* __restrict__ logamp,
                                                   float* __restrict__ out) {
    __shared__ float red[1024];
    const int tid = threadIdx.x;
    const unsigned short* Sf = mws;
    const unsigned short* Rb = mws + MATSZ;
    float part = 0.f;
    for (int j = 0; j < 16; ++j) {
        int idx = tid + j * 1024;
        part += bf2f(Sf[idx]) * bf2f(Rb[idx]);
    }
    red[tid] = part;
    __syncthreads();
    for (int off = 512; off > 0; off >>= 1) {
        if (tid < off) red[tid] += red[tid + off];
        __syncthreads();
    }
    float lz = logf(red[0]) + 256.0f * 1.3862943611198906f;
    out[tid]        = logamp[tid]        - lz;
    out[tid + 1024] = logamp[tid + 1024] - lz;
}

extern "C" void kernel_launch(void* const* d_in, const int* in_sizes, int n_in,
                              void* d_out, int out_size, void* d_ws, size_t ws_size,
                              hipStream_t stream) {
    const int*   xdata = (const int*)d_in[0];
    const float* core  = (const float*)d_in[1];
    const float* edge  = (const float*)d_in[2];
    float* out = (float*)d_out;
    char* ws = (char*)d_ws;

    const size_t need_full  = OFF_BLO + SZ_MAT + SZ_TAIL;
    const size_t need_noblo = OFF_BLO + SZ_TAIL;
    const int use_blo = (ws_size >= need_full) ? 1 : 0;
    if (!use_blo && ws_size < need_noblo) return;

    unsigned short* abf  = (unsigned short*)(ws + OFF_ABF);
    unsigned short* atbf = (unsigned short*)(ws + OFF_ATBF);
    unsigned short* bhi  = (unsigned short*)(ws + OFF_BHI);
    unsigned short* blo  = (unsigned short*)(ws + (use_blo ? OFF_BLO : OFF_BHI));
    const size_t tail = use_blo ? (OFF_BLO + SZ_MAT) : OFF_BLO;
    unsigned short* mws  = (unsigned short*)(ws + tail);
    float* logamp = (float*)(ws + tail + SZ_MWS);

    convert_kernel<<<SEQ * INP, 256, 0, stream>>>(core, abf, atbf, bhi, blo, use_blo);
    if (use_blo)
        main_kernel<1><<<66, 512, 0, stream>>>(xdata, edge, abf, atbf, bhi, blo, mws, logamp);
    else
        main_kernel<0><<<66, 512, 0, stream>>>(xdata, edge, abf, atbf, bhi, blo, mws, logamp);
    fin_kernel<<<1, 1024, 0, stream>>>(mws, logamp, out);
}

// Round 7
// 2611.111 us; speedup vs baseline: 1.0032x; 1.0032x over previous
//
#include <hip/hip_runtime.h>
#include <cstdint>
#include <cstddef>

#define SEQ   256
#define INP   4
#define BOND  128
#define BATCH 2048
#define MATSZ (BOND*BOND)

typedef __bf16 bf16x8 __attribute__((ext_vector_type(8)));
typedef __bf16 bf16x4 __attribute__((ext_vector_type(4)));
typedef float  f32x4  __attribute__((ext_vector_type(4)));
typedef short  s16x4  __attribute__((ext_vector_type(4)));

// ---- workspace layout (bytes) ----
static constexpr size_t SZ_MAT   = (size_t)SEQ*INP*MATSZ*2;   // 32 MiB each
static constexpr size_t OFF_ABF  = 0;
static constexpr size_t OFF_ATBF = OFF_ABF + SZ_MAT;
static constexpr size_t OFF_BHI  = OFF_ATBF + SZ_MAT;
static constexpr size_t OFF_BLO  = OFF_BHI + SZ_MAT;
static constexpr size_t SZ_MWS   = 2ull*MATSZ*2;              // 2 chains final M (bf16, linear)
static constexpr size_t SZ_TAIL  = SZ_MWS + (size_t)BATCH*4 + 64;

static __device__ __forceinline__ unsigned short f2bf(float f) {
    union { float f; uint32_t u; } v; v.f = f;
    uint32_t r = (v.u + 0x7FFFu + ((v.u >> 16) & 1u)) >> 16;   // RNE
    return (unsigned short)r;
}
static __device__ __forceinline__ float bf2f(unsigned short b) {
    union { uint32_t u; float f; } v; v.u = ((uint32_t)b) << 16;
    return v.f;
}
static __device__ __forceinline__ f32x4 mfma16(bf16x8 a, bf16x8 b, f32x4 c) {
    return __builtin_amdgcn_mfma_f32_16x16x32_bf16(a, b, c, 0, 0, 0);
}
#if defined(__has_builtin)
#if __has_builtin(__builtin_amdgcn_mfma_f32_16x16x16bf16_1k)
#define HAVE_MFMA16X16_BUILTIN 1
#endif
#endif
static __device__ __forceinline__ f32x4 mfma16x16(bf16x4 a, bf16x4 b, f32x4 c) {
#ifdef HAVE_MFMA16X16_BUILTIN
    return __builtin_amdgcn_mfma_f32_16x16x16bf16_1k(
        __builtin_bit_cast(s16x4, a), __builtin_bit_cast(s16x4, b), c, 0, 0, 0);
#else
    asm("v_mfma_f32_16x16x16_bf16 %0, %1, %2, %0" : "+v"(c) : "v"(a), "v"(b));
    return c;
#endif
}
static __device__ __forceinline__ unsigned int cvtpk(float a, float b) {
    unsigned int d;
    asm("v_cvt_pk_bf16_f32 %0, %1, %2" : "=v"(d) : "v"(a), "v"(b));
    return d;   // lo16 = bf16(a), hi16 = bf16(b)
}
// XOR-swizzled LDS layout: matrix stored as 16B chunks; chunk (r, c8) at
// slot r*16 + (c8 ^ (r&15)). Returns SHORT index of chunk start.
static __device__ __forceinline__ int xoff(int r, int c8) {
    return ((r << 4) + (c8 ^ (r & 15))) << 3;
}
// async global->LDS 16B, linear LDS dest (lane*16), pre-swizzled global source
static __device__ __forceinline__ void gload_lds16(const unsigned short* g, unsigned short* l) {
    __builtin_amdgcn_global_load_lds((const __attribute__((address_space(1))) unsigned int*)g,
                                     (__attribute__((address_space(3))) unsigned int*)l,
                                     16, 0, 0);
}
// stage one 128x128 bf16 matrix into XOR-swizzled LDS (all 512 threads)
static __device__ __forceinline__ void stage_mat(const unsigned short* __restrict__ Ai,
                                                 unsigned short* dst, int tid) {
#pragma unroll
    for (int j = 0; j < 4; ++j) {
        int slot = j * 512 + tid;
        int r = slot >> 4, c8 = slot & 15;
        const unsigned short* src = Ai + (size_t)r * BOND + ((c8 ^ (r & 15)) << 3);
        unsigned short* ldst = dst + (size_t)(j * 512 + (tid & ~63)) * 8;
        gload_lds16(src, ldst);
    }
}

// ---------------- convert: fp32 core -> bf16 A, bf16 A^T, bf16 hi/lo of (A - I) ----------------
__global__ void convert_kernel(const float* __restrict__ core,
                               unsigned short* __restrict__ abf,
                               unsigned short* __restrict__ atbf,
                               unsigned short* __restrict__ bhi,
                               unsigned short* __restrict__ blo,
                               int use_blo) {
    __shared__ unsigned short tile[BOND][BOND + 2];
    const int mat = blockIdx.x;                       // 0..1023  (t*4+v)
    const float* src = core + (size_t)mat * MATSZ;
    unsigned short* dA = abf  + (size_t)mat * MATSZ;
    unsigned short* dT = atbf + (size_t)mat * MATSZ;
    unsigned short* dH = bhi  + (size_t)mat * MATSZ;
    unsigned short* dL = blo  + (size_t)mat * MATSZ;
    const int tid = threadIdx.x;
    for (int j = 0; j < 16; ++j) {
        int lin4 = (tid + j * 256) * 4;
        float4 f = *(const float4*)(src + lin4);
        int r = lin4 >> 7, c = lin4 & 127;
        unsigned short a0=f2bf(f.x), a1=f2bf(f.y), a2=f2bf(f.z), a3=f2bf(f.w);
        *(ushort4*)(dA + lin4) = make_ushort4(a0,a1,a2,a3);
        tile[r][c]=a0; tile[r][c+1]=a1; tile[r][c+2]=a2; tile[r][c+3]=a3;
        float b0 = f.x - ((r == c    ) ? 1.0f : 0.0f);
        float b1 = f.y - ((r == c + 1) ? 1.0f : 0.0f);
        float b2 = f.z - ((r == c + 2) ? 1.0f : 0.0f);
        float b3 = f.w - ((r == c + 3) ? 1.0f : 0.0f);
        unsigned short h0=f2bf(b0), h1=f2bf(b1), h2=f2bf(b2), h3=f2bf(b3);
        *(ushort4*)(dH + lin4) = make_ushort4(h0,h1,h2,h3);
        if (use_blo) {
            *(ushort4*)(dL + lin4) = make_ushort4(
                f2bf(b0 - bf2f(h0)), f2bf(b1 - bf2f(h1)),
                f2bf(b2 - bf2f(h2)), f2bf(b3 - bf2f(h3)));
        }
    }
    __syncthreads();
    for (int j = 0; j < 16; ++j) {
        int lin4 = (tid + j * 256) * 4;
        int co = lin4 >> 7, r0 = lin4 & 127;
        *(ushort4*)(dT + lin4) = make_ushort4(tile[r0][co], tile[r0+1][co],
                                              tile[r0+2][co], tile[r0+3][co]);
    }
}

// ---------------- main kernel: blocks 0..1 = Z chains, 2..65 = amplitude ----------------
struct ZSm {
    unsigned short As[2][MATSZ];    // double-buffered A_i, XOR layout (64 KB)
    unsigned short M[MATSZ];        // density matrix, XOR layout (32 KB)
    float vec[BOND];
};
struct ASm {
    int   toks[SEQ * 32];           // prefetched tokens (32 KB)
    float hf[32][132];              // fp32 h state [batch-col][dim]
    unsigned short hhi[32 * BOND];  // bf16 hi of h, XOR layout (flat)
    unsigned short hlo[32 * BOND];  // bf16 lo of h, XOR layout (flat)
    float ev[BOND];
    float partial[8][32];
    float sinv[32];
    float logn[32];
};
union SmU { ZSm z; ASm a; };

// launch_bounds(512, 2): min 2 waves/EU (= 1 block/CU) -> VGPR budget 256.
// At the default the compiler capped at 128 VGPR and serialized the 32-fragment
// bulk preload into load->waitcnt->use rounds (~20k cy/step) -- the r5/r6 stall.
template<int USE_BLO>
__global__ __launch_bounds__(512, 2) void main_kernel(
        const int*   __restrict__ xdata,
        const float* __restrict__ edge,
        const unsigned short* __restrict__ abf,
        const unsigned short* __restrict__ atbf,
        const unsigned short* __restrict__ bhi,
        const unsigned short* __restrict__ blo,
        unsigned short* __restrict__ mws,
        float* __restrict__ logamp) {
    __shared__ SmU sm;
    const int tid = threadIdx.x;
    const int l   = tid & 63;
    const int w   = tid >> 6;          // wave 0..7
    const int lo  = l & 15;
    const int hi  = l >> 4;            // 0..3

    if (blockIdx.x < 2) {
        // ================= Z chain: 4 compute waves + 4 stage-helper waves =================
        const int chain = blockIdx.x;                  // 0 = fwd (alpha), 1 = bwd (omega, A^T)
        const unsigned short* Abase = chain ? atbf : abf;

        if (tid < BOND) sm.z.vec[tid] = edge[chain * BOND + tid];
        __syncthreads();
        for (int idx = tid; idx < MATSZ; idx += 512) {
            int r = idx >> 7, c = idx & 127;
            sm.z.M[xoff(r, c >> 3) + (c & 7)] = f2bf(sm.z.vec[r] * sm.z.vec[c]);
        }
        stage_mat(Abase + (size_t)(chain ? (SEQ - 1) : 0) * INP * MATSZ, sm.z.As[0], tid);
        __syncthreads();               // M0 + As[0] ready (full drain, once)

        int cur = 0;
        for (int s = 1; s <= 128; ++s) {
            const int tstep = chain ? (SEQ - s) : (s - 1);
            const unsigned short* As_g = Abase + (size_t)tstep * INP * MATSZ;
            f32x4 accM[2][8];
#pragma unroll
            for (int mt = 0; mt < 2; ++mt)
#pragma unroll
                for (int ct = 0; ct < 8; ++ct) accM[mt][ct] = (f32x4){0.f, 0.f, 0.f, 0.f};

            for (int i = 0; i < 4; ++i) {
                const unsigned short* nxt = nullptr;
                if (i < 3)           nxt = As_g + (size_t)(i + 1) * MATSZ;
                else if (s < 128)    nxt = Abase + (size_t)(chain ? (SEQ - s - 1) : s) * INP * MATSZ;
                if (nxt) stage_mat(nxt, sm.z.As[cur ^ 1], tid);

                if (w < 4) {
                    const unsigned short* Ac = sm.z.As[cur];
                    // ---- P1: C1 = M * A_i^T, swapped so T lands in A-frag layout ----
                    f32x4 acc1[8][2];
#pragma unroll
                    for (int pt = 0; pt < 8; ++pt) {
                        acc1[pt][0] = (f32x4){0.f, 0.f, 0.f, 0.f};
                        acc1[pt][1] = (f32x4){0.f, 0.f, 0.f, 0.f};
                    }
#pragma unroll
                    for (int kk = 0; kk < 4; ++kk) {
                        bf16x8 bq0 = *(const bf16x8*)&Ac[xoff(w * 32 + lo,      kk * 4 + hi)];
                        bf16x8 bq1 = *(const bf16x8*)&Ac[xoff(w * 32 + 16 + lo, kk * 4 + hi)];
#pragma unroll
                        for (int pt = 0; pt < 8; ++pt) {
                            bf16x8 mf = *(const bf16x8*)&sm.z.M[xoff(pt * 16 + lo, kk * 4 + hi)];
                            acc1[pt][0] = mfma16(mf, bq0, acc1[pt][0]);
                            acc1[pt][1] = mfma16(mf, bq1, acc1[pt][1]);
                        }
                    }
                    // ---- convert T to bf16 A-frags in-register ----
                    bf16x4 tf[2][8];
#pragma unroll
                    for (int pt = 0; pt < 8; ++pt)
#pragma unroll
                        for (int mt = 0; mt < 2; ++mt) {
                            union { unsigned int u[2]; bf16x4 v; } pk;
                            pk.u[0] = cvtpk(acc1[pt][mt][0], acc1[pt][mt][1]);
                            pk.u[1] = cvtpk(acc1[pt][mt][2], acc1[pt][mt][3]);
                            tf[mt][pt] = pk.v;
                        }
                    // ---- P2: accM += T * A_i^T  (16x16x16, B = A_i rows, 8B reads) ----
#pragma unroll
                    for (int ks = 0; ks < 8; ++ks) {
#pragma unroll
                        for (int ct = 0; ct < 8; ++ct) {
                            bf16x4 bb = *(const bf16x4*)&Ac[xoff(ct * 16 + lo, 2 * ks + (hi >> 1)) + 4 * (hi & 1)];
                            accM[0][ct] = mfma16x16(tf[0][ks], bb, accM[0][ct]);
                            accM[1][ct] = mfma16x16(tf[1][ks], bb, accM[1][ct]);
                        }
                    }
                }
                asm volatile("s_waitcnt vmcnt(0)" ::: "memory");   // own staged loads landed
                __builtin_amdgcn_s_barrier();                      // all waves' staging visible
                cur ^= 1;
            }
            // ---- step end: write M' (scaled 1/4) ----
            if (w < 4) {
#pragma unroll
                for (int mt = 0; mt < 2; ++mt)
#pragma unroll
                    for (int ct = 0; ct < 8; ++ct)
#pragma unroll
                        for (int r = 0; r < 4; ++r) {
                            int row = w * 32 + mt * 16 + hi * 4 + r;
                            int col = ct * 16 + lo;
                            sm.z.M[xoff(row, col >> 3) + (col & 7)] =
                                f2bf(accM[mt][ct][r] * 0.25f);
                        }
            }
            asm volatile("s_waitcnt lgkmcnt(0)" ::: "memory");
            __builtin_amdgcn_s_barrier();                          // M' visible to all
        }
        // publish final M (XOR layout -> linear global)
        unsigned short* outb = mws + (size_t)chain * MATSZ;
        for (int j = 0; j < 4; ++j) {
            int chunk = tid + j * 512;
            int r = chunk >> 4, c8 = chunk & 15;
            *(bf16x8*)(outb + (size_t)r * BOND + c8 * 8) =
                *(const bf16x8*)&sm.z.M[xoff(r, c8)];
        }
    } else {
        // ================= amplitude scan (structure unchanged from r6) =================
        const int lr = lo, lq = hi;
        const int b0 = (blockIdx.x - 2) * 32;
        for (int j = 0; j < 16; ++j) {
            int idx = tid + j * 512;
            int t = idx >> 5, c = idx & 31;
            sm.a.toks[idx] = xdata[(size_t)t * BATCH + b0 + c];
        }
        if (tid < BOND) sm.a.ev[tid] = edge[tid];      // alpha
        if (tid < 32)  sm.a.logn[tid] = 0.f;
        __syncthreads();
        for (int idx = tid; idx < 32 * BOND; idx += 512) {
            int c = idx >> 7, r = idx & 127;
            float v = sm.a.ev[r];
            unsigned short hh = f2bf(v);
            sm.a.hf[c][r] = v;
            int si = xoff(c, r >> 3) + (r & 7);
            sm.a.hhi[si] = hh;
            sm.a.hlo[si] = f2bf(v - bf2f(hh));
        }
        __syncthreads();

        for (int t = 0; t < SEQ; ++t) {
            const unsigned short* Bh = bhi + (size_t)t * INP * MATSZ;
            const unsigned short* Bl = blo + (size_t)t * INP * MATSZ;
            bf16x8 bh[4][4], bl[4][4];
#pragma unroll
            for (int kk = 0; kk < 4; ++kk)
#pragma unroll
                for (int v = 0; v < 4; ++v) {
                    size_t ro = (size_t)v * MATSZ + (size_t)(w * 16 + lr) * BOND + kk * 32 + lq * 8;
                    bh[kk][v] = *(const bf16x8*)(Bh + ro);
                    if (USE_BLO) bl[kk][v] = *(const bf16x8*)(Bl + ro);
                }
            f32x4 acc[4][2] = {};
#pragma unroll
            for (int kk = 0; kk < 4; ++kk) {
                bf16x8 hh0 = *(const bf16x8*)&sm.a.hhi[xoff(lr,      kk * 4 + lq)];
                bf16x8 hh1 = *(const bf16x8*)&sm.a.hhi[xoff(16 + lr, kk * 4 + lq)];
                bf16x8 hl0 = *(const bf16x8*)&sm.a.hlo[xoff(lr,      kk * 4 + lq)];
                bf16x8 hl1 = *(const bf16x8*)&sm.a.hlo[xoff(16 + lr, kk * 4 + lq)];
#pragma unroll
                for (int v = 0; v < 4; ++v) {
                    acc[v][0] = mfma16(bh[kk][v], hh0, acc[v][0]);
                    acc[v][0] = mfma16(bh[kk][v], hl0, acc[v][0]);
                    acc[v][1] = mfma16(bh[kk][v], hh1, acc[v][1]);
                    acc[v][1] = mfma16(bh[kk][v], hl1, acc[v][1]);
                    if (USE_BLO) {
                        acc[v][0] = mfma16(bl[kk][v], hh0, acc[v][0]);
                        acc[v][1] = mfma16(bl[kk][v], hh1, acc[v][1]);
                    }
                }
            }
            __syncthreads();
            f32x4 h2[2];
#pragma unroll
            for (int ct = 0; ct < 2; ++ct) {
                int tok = sm.a.toks[t * 32 + ct * 16 + lr];
                f32x4 d = acc[0][ct];
                d = (tok == 1) ? acc[1][ct] : d;
                d = (tok == 2) ? acc[2][ct] : d;
                d = (tok == 3) ? acc[3][ct] : d;
                f32x4 ho = *(const f32x4*)&sm.a.hf[ct * 16 + lr][w * 16 + lq * 4];
                h2[ct] = ho + d;
            }
            if ((t & 7) == 7) {
#pragma unroll
                for (int ct = 0; ct < 2; ++ct) {
                    float ss = h2[ct][0]*h2[ct][0] + h2[ct][1]*h2[ct][1]
                             + h2[ct][2]*h2[ct][2] + h2[ct][3]*h2[ct][3];
                    ss += __shfl_xor(ss, 16);
                    ss += __shfl_xor(ss, 32);
                    if (lq == 0) sm.a.partial[w][ct * 16 + lr] = ss;
                }
                __syncthreads();
                if (tid < 32) {
                    float s2 = 0.f;
#pragma unroll
                    for (int w2 = 0; w2 < 8; ++w2) s2 += sm.a.partial[w2][tid];
                    sm.a.sinv[tid] = rsqrtf(s2);
                    sm.a.logn[tid] += 0.5f * logf(s2);
                }
                __syncthreads();
#pragma unroll
                for (int ct = 0; ct < 2; ++ct) h2[ct] *= sm.a.sinv[ct * 16 + lr];
            }
#pragma unroll
            for (int ct = 0; ct < 2; ++ct) {
                int c = ct * 16 + lr;
                *(f32x4*)&sm.a.hf[c][w * 16 + lq * 4] = h2[ct];
                unsigned short q0 = f2bf(h2[ct][0]), q1 = f2bf(h2[ct][1]),
                               q2 = f2bf(h2[ct][2]), q3 = f2bf(h2[ct][3]);
                int c8w = w * 2 + (lq >> 1);
                int si  = xoff(c, c8w) + (lq & 1) * 4;
                *(ushort4*)&sm.a.hhi[si] = make_ushort4(q0, q1, q2, q3);
                *(ushort4*)&sm.a.hlo[si] =
                    make_ushort4(f2bf(h2[ct][0] - bf2f(q0)), f2bf(h2[ct][1] - bf2f(q1)),
                                 f2bf(h2[ct][2] - bf2f(q2)), f2bf(h2[ct][3] - bf2f(q3)));
            }
            __syncthreads();
        }
        if (tid < BOND) sm.a.ev[tid] = edge[BOND + tid];  // omega
        __syncthreads();
        if (tid < 32) {
            float dot = 0.f;
            for (int r = 0; r < BOND; ++r) dot += sm.a.hf[tid][r] * sm.a.ev[r];
            logamp[b0 + tid] = 2.f * (logf(fabsf(dot)) + sm.a.logn[tid]);
        }
    }
}

// ---------------- finalize: logZ = log<M_fwd, M_bwd> + 256*log4; out = logamp - logZ ----------------
__global__ __launch_bounds__(1024) void fin_kernel(const unsigned short* __restrict__ mws,
                                                   const float* __restrict__ logamp,
                                                   float* __restrict__ out) {
    __shared__ float red[1024];
    const int tid = threadIdx.x;
    const unsigned short* Sf = mws;
    const unsigned short* Rb = mws + MATSZ;
    float part = 0.f;
    for (int j = 0; j < 16; ++j) {
        int idx = tid + j * 1024;
        part += bf2f(Sf[idx]) * bf2f(Rb[idx]);
    }
    red[tid] = part;
    __syncthreads();
    for (int off = 512; off > 0; off >>= 1) {
        if (tid < off) red[tid] += red[tid + off];
        __syncthreads();
    }
    float lz = logf(red[0]) + 256.0f * 1.3862943611198906f;
    out[tid]        = logamp[tid]        - lz;
    out[tid + 1024] = logamp[tid + 1024] - lz;
}

extern "C" void kernel_launch(void* const* d_in, const int* in_sizes, int n_in,
                              void* d_out, int out_size, void* d_ws, size_t ws_size,
                              hipStream_t stream) {
    const int*   xdata = (const int*)d_in[0];
    const float* core  = (const float*)d_in[1];
    const float* edge  = (const float*)d_in[2];
    float* out = (float*)d_out;
    char* ws = (char*)d_ws;

    const size_t need_full  = OFF_BLO + SZ_MAT + SZ_TAIL;
    const size_t need_noblo = OFF_BLO + SZ_TAIL;
    const int use_blo = (ws_size >= need_full) ? 1 : 0;
    if (!use_blo && ws_size < need_noblo) return;

    unsigned short* abf  = (unsigned short*)(ws + OFF_ABF);
    unsigned short* atbf = (unsigned short*)(ws + OFF_ATBF);
    unsigned short* bhi  = (unsigned short*)(ws + OFF_BHI);
    unsigned short* blo  = (unsigned short*)(ws + (use_blo ? OFF_BLO : OFF_BHI));
    const size_t tail = use_blo ? (OFF_BLO + SZ_MAT) : OFF_BLO;
    unsigned short* mws  = (unsigned short*)(ws + tail);
    float* logamp = (float*)(ws + tail + SZ_MWS);

    convert_kernel<<<SEQ * INP, 256, 0, stream>>>(core, abf, atbf, bhi, blo, use_blo);
    if (use_blo)
        main_kernel<1><<<66, 512, 0, stream>>>(xdata, edge, abf, atbf, bhi, blo, mws, logamp);
    else
        main_kernel<0><<<66, 512, 0, stream>>>(xdata, edge, abf, atbf, bhi, blo, mws, logamp);
    fin_kernel<<<1, 1024, 0, stream>>>(mws, logamp, out);
}